// Round 1
// baseline (9411.601 us; speedup 1.0000x reference)
//
#include <hip/hip_runtime.h>
#include <hip/hip_bf16.h>
#include <cstdint>
#include <cstddef>

#define BB 64
#define SS 512
#define DD 1024
#define G4 4096  // 4*units

typedef __attribute__((ext_vector_type(8))) short bf16x8;
typedef __attribute__((ext_vector_type(8))) unsigned short u16x8;
typedef __attribute__((ext_vector_type(4))) float f32x4;

static __device__ __forceinline__ unsigned short f2bf(float f) {
  union { float f; uint32_t u; } v; v.f = f;
  uint32_t u = v.u;
  return (unsigned short)((u + 0x7FFFu + ((u >> 16) & 1u)) >> 16);  // RTNE
}

// ---- convert x (f32 -> bf16), vectorized ----
__global__ void cvt_x(const float* __restrict__ in, unsigned short* __restrict__ out, int n8) {
  for (int i = blockIdx.x * blockDim.x + threadIdx.x; i < n8; i += gridDim.x * blockDim.x) {
    const float4* pp = (const float4*)(in + (size_t)i * 8);
    float4 a = pp[0], b2 = pp[1];
    u16x8 o;
    o[0] = f2bf(a.x);  o[1] = f2bf(a.y);  o[2] = f2bf(a.z);  o[3] = f2bf(a.w);
    o[4] = f2bf(b2.x); o[5] = f2bf(b2.y); o[6] = f2bf(b2.z); o[7] = f2bf(b2.w);
    *(u16x8*)(out + (size_t)i * 8) = o;
  }
}

// ---- transpose-convert W,U: in[k][c] f32 -> out[c][k] bf16 ----
__global__ __launch_bounds__(256) void cvt_transpose(
    const float* __restrict__ Win, const float* __restrict__ Uin,
    unsigned short* __restrict__ Wt, unsigned short* __restrict__ Ut) {
  __shared__ float tile[32][33];
  const float* in = blockIdx.z ? Uin : Win;
  unsigned short* out = blockIdx.z ? Ut : Wt;
  int k0 = blockIdx.x * 32;   // K dim (1024): 32 blocks
  int c0 = blockIdx.y * 32;   // col dim (4096): 128 blocks
  int tc = threadIdx.x & 31, tr = threadIdx.x >> 5;  // tr: 0..7
  #pragma unroll
  for (int j = 0; j < 32; j += 8)
    tile[tr + j][tc] = in[(size_t)(k0 + tr + j) * G4 + (c0 + tc)];
  __syncthreads();
  #pragma unroll
  for (int j = 0; j < 32; j += 8)
    out[(size_t)(c0 + tr + j) * DD + (k0 + tc)] = f2bf(tile[tc][tr + j]);
}

// ---- one LSTM timestep ----
// grid: 256 wgs (64 unit-groups x 4 row-groups), block 256 (4 waves = 4 gates)
// wg computes z[16 rows][4 gates x 16 units], K = 1024(x@W) + 1024(h@U)
template <bool XBF>
__global__ __launch_bounds__(256) void lstm_step(
    const unsigned short* __restrict__ xb,  // bf16 [B][S][D] (if XBF)
    const float* __restrict__ xf,           // f32  [B][S][D] (if !XBF)
    const unsigned short* __restrict__ Wt,  // bf16 [4096][1024]  (= W^T)
    const unsigned short* __restrict__ Ut,  // bf16 [4096][1024]  (= U^T)
    const float* __restrict__ bias,         // [4096]
    unsigned short* __restrict__ hbuf,      // bf16 [2][B][D]
    float* __restrict__ cbuf,               // f32 [B][D]
    float* __restrict__ out,                // outputs | ht | ct
    int t) {
  __shared__ float zt[4][16][16];
  const int wg = blockIdx.x;
  const int ugrp = wg >> 2, rgrp = wg & 3;
  const int row0 = rgrp * 16;
  const int ucol0 = ugrp * 16;
  const int wave = threadIdx.x >> 6;  // = gate index 0..3 (i,f,c~,o)
  const int lane = threadIdx.x & 63;
  const int arow = lane & 15;              // A-frag row
  const int k0 = (lane >> 4) * 8;          // A/B-frag k base
  const int gr = row0 + arow;              // global batch row
  const int cg = wave * DD + ucol0 + (lane & 15);  // global gate column

  const unsigned short* hp = hbuf + (size_t)(t & 1) * BB * DD + (size_t)gr * DD + k0;
  const unsigned short* wp = Wt + (size_t)cg * DD + k0;
  const unsigned short* up = Ut + (size_t)cg * DD + k0;

  f32x4 acc = {0.f, 0.f, 0.f, 0.f};

  // x @ W part
  if (XBF) {
    const unsigned short* xp = xb + ((size_t)gr * SS + t) * DD + k0;
    #pragma unroll 8
    for (int kk = 0; kk < DD; kk += 32) {
      bf16x8 a = *(const bf16x8*)(xp + kk);
      bf16x8 b = *(const bf16x8*)(wp + kk);
      acc = __builtin_amdgcn_mfma_f32_16x16x32_bf16(a, b, acc, 0, 0, 0);
    }
  } else {
    const float* xp = xf + ((size_t)gr * SS + t) * DD + k0;
    #pragma unroll 4
    for (int kk = 0; kk < DD; kk += 32) {
      float4 v0 = *(const float4*)(xp + kk);
      float4 v1 = *(const float4*)(xp + kk + 4);
      bf16x8 a;
      a[0] = (short)f2bf(v0.x); a[1] = (short)f2bf(v0.y);
      a[2] = (short)f2bf(v0.z); a[3] = (short)f2bf(v0.w);
      a[4] = (short)f2bf(v1.x); a[5] = (short)f2bf(v1.y);
      a[6] = (short)f2bf(v1.z); a[7] = (short)f2bf(v1.w);
      bf16x8 b = *(const bf16x8*)(wp + kk);
      acc = __builtin_amdgcn_mfma_f32_16x16x32_bf16(a, b, acc, 0, 0, 0);
    }
  }
  // h @ U part
  #pragma unroll 8
  for (int kk = 0; kk < DD; kk += 32) {
    bf16x8 a = *(const bf16x8*)(hp + kk);
    bf16x8 b = *(const bf16x8*)(up + kk);
    acc = __builtin_amdgcn_mfma_f32_16x16x32_bf16(a, b, acc, 0, 0, 0);
  }

  float bv = bias[cg];
  // C/D layout (verified m89/m91): col = lane&15, row = (lane>>4)*4 + j
  #pragma unroll
  for (int j = 0; j < 4; ++j)
    zt[wave][(lane >> 4) * 4 + j][lane & 15] = acc[j] + bv;
  __syncthreads();

  // gate combine: thread -> (row, unit-col) element
  const int r = threadIdx.x >> 4, uc = threadIdx.x & 15;
  float zi = zt[0][r][uc], zf = zt[1][r][uc], zg = zt[2][r][uc], zo = zt[3][r][uc];
  float ig = 1.f / (1.f + __expf(-zi));
  float fg = 1.f / (1.f + __expf(-zf));
  float gg = tanhf(zg);
  float og = 1.f / (1.f + __expf(-zo));
  const int gidx = (row0 + r) * DD + ucol0 + uc;
  float c = fg * cbuf[gidx] + ig * gg;
  cbuf[gidx] = c;
  float h = og * tanhf(c);
  hbuf[(size_t)((t & 1) ^ 1) * BB * DD + gidx] = f2bf(h);
  out[((size_t)(row0 + r) * SS + t) * DD + ucol0 + uc] = h;
  if (t == SS - 1) {
    out[(size_t)BB * SS * DD + gidx] = h;           // ht
    out[(size_t)BB * SS * DD + BB * DD + gidx] = c; // ct
  }
}

extern "C" void kernel_launch(void* const* d_in, const int* in_sizes, int n_in,
                              void* d_out, int out_size, void* d_ws, size_t ws_size,
                              hipStream_t stream) {
  const float* x = (const float*)d_in[0];
  const float* W = (const float*)d_in[1];
  const float* U = (const float*)d_in[2];
  const float* bias = (const float*)d_in[3];
  float* out = (float*)d_out;

  char* p = (char*)d_ws;
  unsigned short* Wt = (unsigned short*)p;  p += (size_t)G4 * DD * 2;      // 8 MB
  unsigned short* Ut = (unsigned short*)p;  p += (size_t)G4 * DD * 2;      // 8 MB
  unsigned short* hbuf = (unsigned short*)p; p += (size_t)2 * BB * DD * 2; // 256 KB
  float* cbuf = (float*)p;                   p += (size_t)BB * DD * 4;     // 256 KB
  unsigned short* xb = (unsigned short*)p;                                 // 64 MB (optional)
  const size_t need_base = (size_t)G4 * DD * 2 * 2 + (size_t)2 * BB * DD * 2 + (size_t)BB * DD * 4;
  const bool xbf = ws_size >= need_base + (size_t)BB * SS * DD * 2;

  // zero h state (both buffers) + c state — contiguous region
  hipMemsetAsync(hbuf, 0, (size_t)2 * BB * DD * 2 + (size_t)BB * DD * 4, stream);

  cvt_transpose<<<dim3(32, 128, 2), 256, 0, stream>>>(W, U, Wt, Ut);
  if (xbf) cvt_x<<<2048, 256, 0, stream>>>(x, xb, BB * SS * DD / 8);

  for (int t = 0; t < SS; ++t) {
    if (xbf)
      lstm_step<true><<<256, 256, 0, stream>>>(xb, nullptr, Wt, Ut, bias, hbuf, cbuf, out, t);
    else
      lstm_step<false><<<256, 256, 0, stream>>>(nullptr, x, Wt, Ut, bias, hbuf, cbuf, out, t);
  }
}

// Round 2
// 3346.463 us; speedup vs baseline: 2.8124x; 2.8124x over previous
//
#include <hip/hip_runtime.h>
#include <hip/hip_bf16.h>
#include <cstdint>
#include <cstddef>

#define BB 64
#define SS 512
#define DD 1024
#define G4 4096  // 4*units

typedef __attribute__((ext_vector_type(8))) short bf16x8;
typedef __attribute__((ext_vector_type(8))) unsigned short u16x8;
typedef __attribute__((ext_vector_type(4))) float f32x4;

static __device__ __forceinline__ unsigned short f2bf(float f) {
  union { float f; uint32_t u; } v; v.f = f;
  uint32_t u = v.u;
  return (unsigned short)((u + 0x7FFFu + ((u >> 16) & 1u)) >> 16);  // RTNE
}
static __device__ __forceinline__ float bf2f(unsigned short s) {
  union { uint32_t u; float f; } v; v.u = ((uint32_t)s) << 16; return v.f;
}

// ---- convert x (f32 -> bf16), vectorized ----
__global__ void cvt_x(const float* __restrict__ in, unsigned short* __restrict__ out, int n8) {
  for (int i = blockIdx.x * blockDim.x + threadIdx.x; i < n8; i += gridDim.x * blockDim.x) {
    const float4* pp = (const float4*)(in + (size_t)i * 8);
    float4 a = pp[0], b2 = pp[1];
    u16x8 o;
    o[0] = f2bf(a.x);  o[1] = f2bf(a.y);  o[2] = f2bf(a.z);  o[3] = f2bf(a.w);
    o[4] = f2bf(b2.x); o[5] = f2bf(b2.y); o[6] = f2bf(b2.z); o[7] = f2bf(b2.w);
    *(u16x8*)(out + (size_t)i * 8) = o;
  }
}

// ---- transpose-convert W,U: in[k][c] f32 -> out[c][k] bf16 ----
__global__ __launch_bounds__(256) void cvt_transpose(
    const float* __restrict__ Win, const float* __restrict__ Uin,
    unsigned short* __restrict__ Wt, unsigned short* __restrict__ Ut) {
  __shared__ float tile[32][33];
  const float* in = blockIdx.z ? Uin : Win;
  unsigned short* out = blockIdx.z ? Ut : Wt;
  int k0 = blockIdx.x * 32;
  int c0 = blockIdx.y * 32;
  int tc = threadIdx.x & 31, tr = threadIdx.x >> 5;
  #pragma unroll
  for (int j = 0; j < 32; j += 8)
    tile[tr + j][tc] = in[(size_t)(k0 + tr + j) * G4 + (c0 + tc)];
  __syncthreads();
  #pragma unroll
  for (int j = 0; j < 32; j += 8)
    out[(size_t)(c0 + tr + j) * DD + (k0 + tc)] = f2bf(tile[tc][tr + j]);
}

// ---- pack Ut[col][k] into MFMA B-fragment order ----
// Up[(((u*4+g)*32+kk)*64+lane)*8 + j] = U[kk*32+(lane>>4)*8+j][g*1024+u*16+(lane&15)]
__global__ __launch_bounds__(256) void pack_u(const unsigned short* __restrict__ Ut,
                                              unsigned short* __restrict__ Up) {
  int tid = blockIdx.x * 256 + threadIdx.x;  // 64*4*32*64 = 524288 total
  int l = tid & 63;
  int kk = (tid >> 6) & 31;
  int g = (tid >> 11) & 3;
  int u = tid >> 13;
  int col = g * DD + u * 16 + (l & 15);
  int k = kk * 32 + (l >> 4) * 8;
  bf16x8 v = *(const bf16x8*)(Ut + (size_t)col * DD + k);
  *(bf16x8*)(Up + (size_t)tid * 8) = v;
}

// ---- xproj GEMM: xproj[t][b][g] = x[b][t][:] @ W[:, g] + bias[g], bf16 out ----
// 128x128 tile, BK=64, 4 waves (2x2), XOR-swizzled LDS, reg-prefetch pipeline.
__global__ __launch_bounds__(256) void gemm_xproj(
    const unsigned short* __restrict__ xb,   // bf16 [32768][1024]
    const unsigned short* __restrict__ Wt,   // bf16 [4096][1024]
    const float* __restrict__ bias,
    unsigned short* __restrict__ xproj) {    // bf16 [512][64][4096]
  __shared__ unsigned short As[128 * 64], Bs[128 * 64];  // 16 KB each
  const int tid = threadIdx.x;
  const int wave = tid >> 6, lane = tid & 63;
  const int wr = wave >> 1, wc = wave & 1;
  const int m0 = blockIdx.x * 128, n0 = blockIdx.y * 128;

  // staging map: thread -> (row = tid>>1, half = tid&1), 4 x 16B chunks
  const int srow = tid >> 1, shalf = tid & 1;
  const unsigned short* ga = xb + (size_t)(m0 + srow) * DD + shalf * 32;
  const unsigned short* gb = Wt + (size_t)(n0 + srow) * DD + shalf * 32;

  bf16x8 ra[4], rb[4];
  #pragma unroll
  for (int c = 0; c < 4; ++c) {
    ra[c] = *(const bf16x8*)(ga + c * 8);
    rb[c] = *(const bf16x8*)(gb + c * 8);
  }

  f32x4 acc[4][4];
  #pragma unroll
  for (int m = 0; m < 4; ++m)
    #pragma unroll
    for (int n = 0; n < 4; ++n) acc[m][n] = (f32x4){0.f, 0.f, 0.f, 0.f};

  char* asb = (char*)As;
  char* bsb = (char*)Bs;

  for (int kt = 0; kt < DD / 64; ++kt) {
    __syncthreads();  // previous tile's reads done
    #pragma unroll
    for (int c = 0; c < 4; ++c) {
      int wb = srow * 128 + ((shalf * 64 + c * 16) ^ ((srow & 7) << 4));
      *(bf16x8*)(asb + wb) = ra[c];
      *(bf16x8*)(bsb + wb) = rb[c];
    }
    __syncthreads();
    if (kt + 1 < DD / 64) {  // prefetch next tile into regs (overlaps MFMA)
      #pragma unroll
      for (int c = 0; c < 4; ++c) {
        ra[c] = *(const bf16x8*)(ga + (kt + 1) * 64 + c * 8);
        rb[c] = *(const bf16x8*)(gb + (kt + 1) * 64 + c * 8);
      }
    }
    #pragma unroll
    for (int kh = 0; kh < 2; ++kh) {
      bf16x8 af[4], bfr[4];
      const int kb = kh * 64 + (lane >> 4) * 16;
      #pragma unroll
      for (int m = 0; m < 4; ++m) {
        int row = wr * 64 + m * 16 + (lane & 15);
        af[m] = *(const bf16x8*)(asb + row * 128 + (kb ^ ((row & 7) << 4)));
        int coln = wc * 64 + m * 16 + (lane & 15);
        bfr[m] = *(const bf16x8*)(bsb + coln * 128 + (kb ^ ((coln & 7) << 4)));
      }
      #pragma unroll
      for (int m = 0; m < 4; ++m)
        #pragma unroll
        for (int n = 0; n < 4; ++n)
          acc[m][n] = __builtin_amdgcn_mfma_f32_16x16x32_bf16(af[m], bfr[n], acc[m][n], 0, 0, 0);
    }
  }

  #pragma unroll
  for (int n = 0; n < 4; ++n) {
    int col = n0 + wc * 64 + n * 16 + (lane & 15);
    float bv = bias[col];
    #pragma unroll
    for (int m = 0; m < 4; ++m) {
      #pragma unroll
      for (int j = 0; j < 4; ++j) {
        int mrow = m0 + wr * 64 + m * 16 + (lane >> 4) * 4 + j;
        int b = mrow >> 9, t = mrow & 511;
        xproj[((size_t)t * BB + b) * G4 + col] = f2bf(acc[m][n][j] + bv);
      }
    }
  }
}

// ---- one LSTM timestep, packed-fragment operands, z = xproj + h@U ----
// grid 256 (ugrp 64 x rgrp 4), block 256 (4 waves = 4 gates)
__global__ __launch_bounds__(256) void lstm_step2(
    const unsigned short* __restrict__ xproj,  // bf16 [512][64][4096], bias folded
    const unsigned short* __restrict__ Up,     // packed B-frags
    const unsigned short* __restrict__ hp,     // packed A-frags (read)
    unsigned short* __restrict__ hn,           // packed A-frags (write)
    float* __restrict__ cbuf,
    float* __restrict__ out,
    int t) {
  __shared__ float zt[4][16][16];
  const int wg = blockIdx.x;
  const int ugrp = wg >> 2, rgrp = wg & 3;
  const int wave = threadIdx.x >> 6, lane = threadIdx.x & 63;

  const unsigned short* ap = hp + ((size_t)(rgrp * 32) * 64 + lane) * 8;
  const unsigned short* bp = Up + ((size_t)(ugrp * 4 + wave) * 32 * 64 + lane) * 8;

  f32x4 acc[4];
  #pragma unroll
  for (int q = 0; q < 4; ++q) acc[q] = (f32x4){0.f, 0.f, 0.f, 0.f};
  #pragma unroll
  for (int kk = 0; kk < 32; ++kk) {
    bf16x8 a = *(const bf16x8*)(ap + kk * 512);
    bf16x8 b = *(const bf16x8*)(bp + kk * 512);
    acc[kk & 3] = __builtin_amdgcn_mfma_f32_16x16x32_bf16(a, b, acc[kk & 3], 0, 0, 0);
  }
  f32x4 z4 = acc[0] + acc[1] + acc[2] + acc[3];
  #pragma unroll
  for (int j = 0; j < 4; ++j)
    zt[wave][(lane >> 4) * 4 + j][lane & 15] = z4[j];
  __syncthreads();

  const int r = threadIdx.x >> 4, uc = threadIdx.x & 15;
  const int row = rgrp * 16 + r;
  const int unit = ugrp * 16 + uc;
  const unsigned short* xp = xproj + ((size_t)t * BB + row) * G4 + unit;
  float zi = zt[0][r][uc] + bf2f(xp[0]);
  float zf = zt[1][r][uc] + bf2f(xp[DD]);
  float zg = zt[2][r][uc] + bf2f(xp[2 * DD]);
  float zo = zt[3][r][uc] + bf2f(xp[3 * DD]);
  float ig = 1.f / (1.f + __expf(-zi));
  float fg = 1.f / (1.f + __expf(-zf));
  float gg = tanhf(zg);
  float og = 1.f / (1.f + __expf(-zo));
  const int gidx = row * DD + unit;
  float c = fg * cbuf[gidx] + ig * gg;
  cbuf[gidx] = c;
  float h = og * tanhf(c);
  out[((size_t)row * SS + t) * DD + unit] = h;
  const int kk2 = unit >> 5, hi = (unit >> 3) & 3, jj = unit & 7;
  hn[((size_t)(rgrp * 32 + kk2) * 64 + hi * 16 + r) * 8 + jj] = f2bf(h);
  if (t == SS - 1) {
    const size_t S0 = (size_t)BB * SS * DD;
    out[S0 + gidx] = h;
    out[S0 + (size_t)BB * DD + gidx] = c;
  }
}

// ---- round-1 step kernel kept as ws-size fallback ----
template <bool XBF>
__global__ __launch_bounds__(256) void lstm_step(
    const unsigned short* __restrict__ xb, const float* __restrict__ xf,
    const unsigned short* __restrict__ Wt, const unsigned short* __restrict__ Ut,
    const float* __restrict__ bias, unsigned short* __restrict__ hbuf,
    float* __restrict__ cbuf, float* __restrict__ out, int t) {
  __shared__ float zt[4][16][16];
  const int wg = blockIdx.x;
  const int ugrp = wg >> 2, rgrp = wg & 3;
  const int row0 = rgrp * 16;
  const int ucol0 = ugrp * 16;
  const int wave = threadIdx.x >> 6;
  const int lane = threadIdx.x & 63;
  const int arow = lane & 15;
  const int k0 = (lane >> 4) * 8;
  const int gr = row0 + arow;
  const int cg = wave * DD + ucol0 + (lane & 15);

  const unsigned short* hp = hbuf + (size_t)(t & 1) * BB * DD + (size_t)gr * DD + k0;
  const unsigned short* wp = Wt + (size_t)cg * DD + k0;
  const unsigned short* up = Ut + (size_t)cg * DD + k0;

  f32x4 acc = {0.f, 0.f, 0.f, 0.f};
  if (XBF) {
    const unsigned short* xp = xb + ((size_t)gr * SS + t) * DD + k0;
    #pragma unroll 8
    for (int kk = 0; kk < DD; kk += 32) {
      bf16x8 a = *(const bf16x8*)(xp + kk);
      bf16x8 b = *(const bf16x8*)(wp + kk);
      acc = __builtin_amdgcn_mfma_f32_16x16x32_bf16(a, b, acc, 0, 0, 0);
    }
  } else {
    const float* xp = xf + ((size_t)gr * SS + t) * DD + k0;
    #pragma unroll 4
    for (int kk = 0; kk < DD; kk += 32) {
      float4 v0 = *(const float4*)(xp + kk);
      float4 v1 = *(const float4*)(xp + kk + 4);
      bf16x8 a;
      a[0] = (short)f2bf(v0.x); a[1] = (short)f2bf(v0.y);
      a[2] = (short)f2bf(v0.z); a[3] = (short)f2bf(v0.w);
      a[4] = (short)f2bf(v1.x); a[5] = (short)f2bf(v1.y);
      a[6] = (short)f2bf(v1.z); a[7] = (short)f2bf(v1.w);
      bf16x8 b = *(const bf16x8*)(wp + kk);
      acc = __builtin_amdgcn_mfma_f32_16x16x32_bf16(a, b, acc, 0, 0, 0);
    }
  }
  #pragma unroll 8
  for (int kk = 0; kk < DD; kk += 32) {
    bf16x8 a = *(const bf16x8*)(hp + kk);
    bf16x8 b = *(const bf16x8*)(up + kk);
    acc = __builtin_amdgcn_mfma_f32_16x16x32_bf16(a, b, acc, 0, 0, 0);
  }

  float bv = bias[cg];
  #pragma unroll
  for (int j = 0; j < 4; ++j)
    zt[wave][(lane >> 4) * 4 + j][lane & 15] = acc[j] + bv;
  __syncthreads();

  const int r = threadIdx.x >> 4, uc = threadIdx.x & 15;
  float zi = zt[0][r][uc], zf = zt[1][r][uc], zg = zt[2][r][uc], zo = zt[3][r][uc];
  float ig = 1.f / (1.f + __expf(-zi));
  float fg = 1.f / (1.f + __expf(-zf));
  float gg = tanhf(zg);
  float og = 1.f / (1.f + __expf(-zo));
  const int gidx = (row0 + r) * DD + ucol0 + uc;
  float c = fg * cbuf[gidx] + ig * gg;
  cbuf[gidx] = c;
  float h = og * tanhf(c);
  hbuf[(size_t)((t & 1) ^ 1) * BB * DD + gidx] = f2bf(h);
  out[((size_t)(row0 + r) * SS + t) * DD + ucol0 + uc] = h;
  if (t == SS - 1) {
    out[(size_t)BB * SS * DD + gidx] = h;
    out[(size_t)BB * SS * DD + BB * DD + gidx] = c;
  }
}

extern "C" void kernel_launch(void* const* d_in, const int* in_sizes, int n_in,
                              void* d_out, int out_size, void* d_ws, size_t ws_size,
                              hipStream_t stream) {
  const float* x = (const float*)d_in[0];
  const float* W = (const float*)d_in[1];
  const float* U = (const float*)d_in[2];
  const float* bias = (const float*)d_in[3];
  float* out = (float*)d_out;
  char* ws = (char*)d_ws;

  // layout: Wt | Ut | h0 | h1 | cbuf | xb | Up | xproj
  const size_t oWt = 0;
  const size_t oUt = oWt + (size_t)G4 * DD * 2;           // 8 MB
  const size_t oH0 = oUt + (size_t)G4 * DD * 2;           // 8 MB
  const size_t oH1 = oH0 + (size_t)BB * DD * 2;           // 128 KB
  const size_t oC  = oH1 + (size_t)BB * DD * 2;           // 128 KB
  const size_t oXb = oC  + (size_t)BB * DD * 4;           // 256 KB
  const size_t oUp = oXb + (size_t)BB * SS * DD * 2;      // 64 MB
  const size_t oXp = oUp + (size_t)G4 * DD * 2;           // 8 MB
  const size_t needFull = oXp + (size_t)SS * BB * G4 * 2; // + 256 MB
  const size_t needR1x = oUp;

  unsigned short* Wt = (unsigned short*)(ws + oWt);
  unsigned short* Ut = (unsigned short*)(ws + oUt);
  unsigned short* h0 = (unsigned short*)(ws + oH0);
  unsigned short* h1 = (unsigned short*)(ws + oH1);
  float* cbuf = (float*)(ws + oC);
  unsigned short* xb = (unsigned short*)(ws + oXb);
  unsigned short* Up = (unsigned short*)(ws + oUp);
  unsigned short* xproj = (unsigned short*)(ws + oXp);

  if (ws_size >= needFull) {
    hipMemsetAsync(h0, 0, (size_t)BB * DD * 2, stream);
    hipMemsetAsync(cbuf, 0, (size_t)BB * DD * 4, stream);
    cvt_transpose<<<dim3(32, 128, 2), 256, 0, stream>>>(W, U, Wt, Ut);
    pack_u<<<2048, 256, 0, stream>>>(Ut, Up);
    cvt_x<<<2048, 256, 0, stream>>>(x, xb, BB * SS * DD / 8);
    gemm_xproj<<<dim3(256, 32), 256, 0, stream>>>(xb, Wt, bias, xproj);
    for (int t = 0; t < SS; ++t) {
      unsigned short* hp = (t & 1) ? h1 : h0;
      unsigned short* hn = (t & 1) ? h0 : h1;
      lstm_step2<<<256, 256, 0, stream>>>(xproj, Up, hp, hn, cbuf, out, t);
    }
  } else {
    // fallback: round-1 structure
    unsigned short* hbuf = h0;  // h0|h1 contiguous = double-buffered hbuf
    const bool xbf = ws_size >= needR1x;
    hipMemsetAsync(hbuf, 0, (size_t)2 * BB * DD * 2 + (size_t)BB * DD * 4, stream);
    cvt_transpose<<<dim3(32, 128, 2), 256, 0, stream>>>(W, U, Wt, Ut);
    if (xbf) cvt_x<<<2048, 256, 0, stream>>>(x, xb, BB * SS * DD / 8);
    for (int t = 0; t < SS; ++t) {
      if (xbf)
        lstm_step<true><<<256, 256, 0, stream>>>(xb, nullptr, Wt, Ut, bias, hbuf, cbuf, out, t);
      else
        lstm_step<false><<<256, 256, 0, stream>>>(nullptr, x, Wt, Ut, bias, hbuf, cbuf, out, t);
    }
  }
}